// Round 3
// baseline (762.707 us; speedup 1.0000x reference)
//
#include <hip/hip_runtime.h>
#include <stdint.h>

#define N_BOXES 6000
#define NT 94            // ceil(6000/64) tiles of 64
#define R  NT            // u64 words per mask row (row pitch = 752 B, 16B-aligned)
#define IOU_THR 0.5f
#define CONF_THR 0.6f

typedef unsigned long long u64;
typedef __attribute__((address_space(1))) const unsigned int glb_u32;
typedef __attribute__((address_space(3))) unsigned int lds_u32;

__device__ __forceinline__ u64 rdlane64(u64 v, int l) {
    unsigned lo = (unsigned)__builtin_amdgcn_readlane((int)(unsigned)v, l);
    unsigned hi = (unsigned)__builtin_amdgcn_readlane((int)(unsigned)(v >> 32), l);
    return ((u64)hi << 32) | lo;
}

// ---- kernel 1: keys + zero ranks ------------------------------------------
// scores uniform [0,1) -> raw float bits monotone. key = (~bits<<32)|index:
// ascending u64 == descending score, ties by ascending index (JAX stable argsort).
__global__ void k_prep(const float* __restrict__ scores, u64* __restrict__ keys,
                       int* __restrict__ rank) {
    int i = blockIdx.x * blockDim.x + threadIdx.x;
    if (i < N_BOXES) {
        unsigned inv = ~__float_as_uint(scores[i]);
        keys[i] = ((u64)inv << 32) | (unsigned)i;
        rank[i] = 0;
    }
}

// ---- kernel 2: partial rank counts (2D: 24 i-blocks x 8 j-segments) -------
__global__ void __launch_bounds__(256) k_count(const u64* __restrict__ keys,
                                               int* __restrict__ rank) {
    __shared__ u64 kt[750];
    const int tid = threadIdx.x;
    const int i = blockIdx.x * 256 + tid;
    const int j0 = blockIdx.y * 750;
    for (int k = tid; k < 750; k += 256) kt[k] = keys[j0 + k];
    __syncthreads();
    u64 mykey = (i < N_BOXES) ? keys[i] : 0ull;
    int cnt = 0;
#pragma unroll 10
    for (int jj = 0; jj < 750; ++jj) cnt += (kt[jj] < mykey) ? 1 : 0;
    if (i < N_BOXES) atomicAdd(&rank[i], cnt);
}

// ---- kernel 3: scatter into sorted order ----------------------------------
__global__ void k_scatter(const int* __restrict__ rank, const float4* __restrict__ boxes,
                          int* __restrict__ sidx, float4* __restrict__ sboxes) {
    int i = blockIdx.x * blockDim.x + threadIdx.x;
    if (i < N_BOXES) {
        int r = rank[i];              // keys distinct -> permutation
        sidx[r] = i;
        sboxes[r] = boxes[i];
    }
}

// ---- kernel 4: pairwise IoU suppression bitmask ---------------------------
__global__ void k_mask(const float4* __restrict__ sboxes, u64* __restrict__ mask,
                       u64* __restrict__ diagw) {
    int ct = blockIdx.x, rt = blockIdx.y;
    if (ct < rt) return;
    int lane = threadIdx.x;
    __shared__ float4 rb[64];
    int row0 = rt * 64;
    int rows = min(64, N_BOXES - row0);
    if (lane < rows) rb[lane] = sboxes[row0 + lane];
    __syncthreads();
    int j = ct * 64 + lane;
    bool jvalid = (j < N_BOXES);
    float4 cb = make_float4(0.f, 0.f, 1.f, 1.f);
    if (jvalid) cb = sboxes[j];
    float carea = (cb.z - cb.x) * (cb.w - cb.y);
    bool isdiag = (ct == rt);
    for (int i = 0; i < rows; ++i) {
        float4 rbx = rb[i];
        float rarea = (rbx.z - rbx.x) * (rbx.w - rbx.y);
        // identical f32 op order as the reference (_pairwise_iou)
        float iw = fmaxf(fminf(rbx.z, cb.z) - fmaxf(rbx.x, cb.x), 0.f);
        float ih = fmaxf(fminf(rbx.w, cb.w) - fmaxf(rbx.y, cb.y), 0.f);
        float inter = iw * ih;
        float iou = inter / ((rarea + carea) - inter);
        int row = row0 + i;
        bool pred = jvalid && (j > row) && (iou > IOU_THR);
        u64 bal = __ballot(pred);
        if (lane == (i & 63)) {
            mask[(u64)row * R + ct] = bal;
            if (isdiag) diagw[row] = bal;
        }
    }
}

// ---- kernel 5: greedy scan — ONE WAVE, async LDS row staging --------------
// Lane l owns removed-words {2l, 2l+1} in registers. Per tile:
//  (a) candidates = valid & ~removed[t]  (superset of kept, known early)
//  (b) fire one global_load_lds (16B/lane -> whole 752B row) per candidate:
//      zero VGPR cost, all loads in flight concurrently
//  (c) serial greedy diag resolve (the true dependency) overlaps the loads
//  (d) single s_waitcnt vmcnt(0), then one ds_read_b128/lane per slot,
//      masked-OR by kept bit into register state.
// NOTE: lanes 47..63 read past the 94-word row (into the next row / 272 B
// into diagw at the very end) — those words land in register slots >=94
// that are never consumed; all addresses stay inside d_ws.
__global__ void __launch_bounds__(64) k_scan(const u64* __restrict__ mask,
                                             const u64* __restrict__ diagw,
                                             u64* __restrict__ keepbits) {
    __shared__ u64 rowbuf[64 * 128];         // 64 slots x 1 KiB
    const int lane = threadIdx.x;
    u64 r0 = 0, r1 = 0;                      // removed words 2*lane, 2*lane+1
    u64 d_cur = diagw[lane];                 // tile 0 diag words
    const char* maskb = (const char*)mask;
    for (int t = 0; t < NT; ++t) {
        const int tn = (t + 1 < NT) ? (t + 1) : 0;
        u64 d_next = diagw[tn * 64 + lane];  // prefetch next tile's diag

        const int row0 = t * 64;
        const int rows = (N_BOXES - row0 >= 64) ? 64 : (N_BOXES - row0);
        const u64 valid = (rows == 64) ? ~0ull : ((1ull << rows) - 1ull);

        u64 curw = rdlane64((t & 1) ? r1 : r0, t >> 1);
        u64 cand = valid & ~curw;

        // (b) async full-row loads for all candidates
        {
            u64 tmp = cand; int s = 0;
            while (tmp) {
                int f = (int)__builtin_ctzll(tmp); tmp &= tmp - 1ull;
                const char* g = maskb + (u64)(row0 + f) * 752 + lane * 16;
                __builtin_amdgcn_global_load_lds(
                    (const glb_u32*)g,
                    (lds_u32*)&rowbuf[s * 128 + lane * 2], 16, 0, 0);
                ++s;
            }
        }

        // (c) serial greedy resolve of the diagonal word
        u64 kw = 0;
        {
            u64 c = cand;
            while (c) {
                int f = (int)__builtin_ctzll(c);
                kw |= (1ull << f);
                u64 df = rdlane64(d_cur, f);
                c &= ~(df | (1ull << f));
            }
        }
        if (lane == 0) keepbits[t] = kw;     // fire-and-forget

        // (d) drain the async queue once, then masked LDS ORs
        asm volatile("s_waitcnt vmcnt(0)" ::: "memory");
        {
            u64 tmp = cand; int s = 0;
            while (tmp) {
                int f = (int)__builtin_ctzll(tmp); tmp &= tmp - 1ull;
                u64 m = ((kw >> f) & 1ull) ? ~0ull : 0ull;
                const u64* p = &rowbuf[s * 128 + lane * 2];   // ds_read_b128
                r0 |= p[0] & m;
                r1 |= p[1] & m;
                ++s;
            }
        }
        d_cur = d_next;
    }
}

// ---- kernel 6: epilogue ---------------------------------------------------
__global__ void k_out(const int* __restrict__ sidx, const float* __restrict__ scores,
                      const u64* __restrict__ keepbits, float* __restrict__ out) {
    int p = blockIdx.x * blockDim.x + threadIdx.x;
    if (p < N_BOXES) {
        int orig = sidx[p];
        float s = scores[orig];
        bool k = (keepbits[p >> 6] >> (p & 63)) & 1ull;
        out[orig] = (k && (s >= CONF_THR)) ? s : 0.0f;  // writes ALL outputs (d_out poisoned)
    }
}

extern "C" void kernel_launch(void* const* d_in, const int* in_sizes, int n_in,
                              void* d_out, int out_size, void* d_ws, size_t ws_size,
                              hipStream_t stream) {
    const float* boxes  = (const float*)d_in[0];    // [6000,4]
    const float* scores = (const float*)d_in[1];    // [6000]
    float* out = (float*)d_out;                     // [6000]

    // workspace layout (scan's 272 B tail over-read lands in diagw: benign)
    char* ws = (char*)d_ws;
    u64*    mask     = (u64*)(ws);                   // 6000*94*8 = 4,512,000 B
    u64*    diagw    = (u64*)(ws + 4512000);         // 94*64*8   =    48,128 B
    u64*    keys     = (u64*)(ws + 4560128);         // 48,000 B
    int*    rank     = (int*)(ws + 4608128);         // 24,000 B
    int*    sidx     = (int*)(ws + 4632128);         // 24,000 B
    float4* sboxes   = (float4*)(ws + 4656128);      // 96,000 B (16B aligned)
    u64*    keepbits = (u64*)(ws + 4752128);         // 752 B

    k_prep   <<<dim3(24), dim3(256), 0, stream>>>(scores, keys, rank);
    k_count  <<<dim3(24, 8), dim3(256), 0, stream>>>(keys, rank);
    k_scatter<<<dim3(24), dim3(256), 0, stream>>>(rank, (const float4*)boxes, sidx, sboxes);
    k_mask   <<<dim3(NT, NT), dim3(64), 0, stream>>>(sboxes, mask, diagw);
    k_scan   <<<dim3(1), dim3(64), 0, stream>>>(mask, diagw, keepbits);
    k_out    <<<dim3(24), dim3(256), 0, stream>>>(sidx, scores, keepbits, out);
}

// Round 4
// 360.322 us; speedup vs baseline: 2.1167x; 2.1167x over previous
//
#include <hip/hip_runtime.h>
#include <stdint.h>

#define N_BOXES 6000
#define NT 94            // ceil(6000/64) tiles of 64
#define R  94            // u64 words per mask row
#define IOU_THR 0.5f
#define CONF_THR 0.6f

typedef unsigned long long u64;

__device__ __forceinline__ u64 rdlane64(u64 v, int l) {
    unsigned lo = (unsigned)__builtin_amdgcn_readlane((int)(unsigned)v, l);
    unsigned hi = (unsigned)__builtin_amdgcn_readlane((int)(unsigned)(v >> 32), l);
    return ((u64)hi << 32) | lo;
}

// ---- kernel 1: fused sort (keys + rank + scatter) -------------------------
// scores uniform [0,1) -> raw float bits monotone. key = (~bits<<32)|index:
// ascending u64 == descending score, ties by ascending index (JAX stable argsort).
// 94 blocks x 256 threads: block b ranks boxes [b*64, b*64+64); each of 4
// waves counts a 1500-key segment from an LDS-resident copy of all keys.
__global__ void __launch_bounds__(256) k_sort(const float* __restrict__ scores,
                                              const float4* __restrict__ boxes,
                                              int* __restrict__ sidx,
                                              float4* __restrict__ sboxes) {
    __shared__ u64 kt[N_BOXES];      // 48,000 B
    __shared__ int part[256];
    const int tid = threadIdx.x;
    for (int j = tid; j < N_BOXES; j += 256) {
        unsigned inv = ~__float_as_uint(scores[j]);
        kt[j] = ((u64)inv << 32) | (unsigned)j;
    }
    __syncthreads();
    const int il = tid & 63;
    const int i = blockIdx.x * 64 + il;
    const int j0 = (tid >> 6) * 1500;        // 4 segments of 1500
    u64 mykey = (i < N_BOXES) ? kt[i] : 0ull;
    int cnt = 0;
#pragma unroll 8
    for (int jj = 0; jj < 1500; ++jj)
        cnt += (kt[j0 + jj] < mykey) ? 1 : 0;
    part[tid] = cnt;
    __syncthreads();
    if (tid < 64 && i < N_BOXES) {
        int r = part[il] + part[64 + il] + part[128 + il] + part[192 + il];
        sidx[r] = i;                 // keys distinct -> permutation
        sboxes[r] = boxes[i];
    }
}

// ---- kernel 2: pairwise IoU suppression bitmask ---------------------------
// block = 1 wave. block (ct, rt): lane = column box, loop rows.
// mask[row][ct] bit b set iff iou(row, ct*64+b) > 0.5 and col > row.
__global__ void k_mask(const float4* __restrict__ sboxes, u64* __restrict__ mask,
                       u64* __restrict__ diagw) {
    int ct = blockIdx.x, rt = blockIdx.y;
    if (ct < rt) return;
    int lane = threadIdx.x;
    __shared__ float4 rb[64];
    int row0 = rt * 64;
    int rows = min(64, N_BOXES - row0);
    if (lane < rows) rb[lane] = sboxes[row0 + lane];
    __syncthreads();
    int j = ct * 64 + lane;
    bool jvalid = (j < N_BOXES);
    float4 cb = make_float4(0.f, 0.f, 1.f, 1.f);
    if (jvalid) cb = sboxes[j];
    float carea = (cb.z - cb.x) * (cb.w - cb.y);
    bool isdiag = (ct == rt);
    for (int i = 0; i < rows; ++i) {
        float4 rbx = rb[i];
        float rarea = (rbx.z - rbx.x) * (rbx.w - rbx.y);
        // identical f32 op order as the reference (_pairwise_iou)
        float iw = fmaxf(fminf(rbx.z, cb.z) - fmaxf(rbx.x, cb.x), 0.f);
        float ih = fmaxf(fminf(rbx.w, cb.w) - fmaxf(rbx.y, cb.y), 0.f);
        float inter = iw * ih;
        float iou = inter / ((rarea + carea) - inter);
        int row = row0 + i;
        bool pred = jvalid && (j > row) && (iou > IOU_THR);
        u64 bal = __ballot(pred);
        if (lane == (i & 63)) {
            mask[(u64)row * R + ct] = bal;
            if (isdiag) diagw[row] = bal;
        }
    }
}

// ---- kernel 3: greedy scan + epilogue — 16 waves, TLP latency hiding ------
// Per tile t: thread (rg=tid>>7, wi=tid&127) UNCONDITIONALLY loads the mask
// words of rows rg*8..rg*8+7 at column t+1+wi (8 independent loads, no
// dependence on the resolve). Wave 0 concurrently does the serial greedy
// resolve of the diagonal word (the algorithm's only true dependency) from
// register-held diag words. One barrier, then each thread ORs its 8 words
// masked by the keep bits and atomicOrs once into LDS removed[].
// Rows >= N_BOXES / cols >= NT read benign in-workspace garbage that the
// keep/valid masks zero out.
__global__ void __launch_bounds__(1024) k_scan(const u64* __restrict__ mask,
                                               const u64* __restrict__ diagw,
                                               const int* __restrict__ sidx,
                                               const float* __restrict__ scores,
                                               float* __restrict__ out) {
    __shared__ u64 removed[NT];
    __shared__ u64 kwbuf[NT];
    __shared__ u64 kw_slot;
    const int tid  = threadIdx.x;
    const int lane = tid & 63;
    const int wave = tid >> 6;
    const int wi   = tid & 127;      // word slot (covers up to 128 >= 93)
    const int rg   = tid >> 7;       // row group 0..7 (8 rows each)
    if (tid < NT) removed[tid] = 0;
    u64 d_cur = (wave == 0) ? diagw[lane] : 0ull;   // tile 0 diag words
    __syncthreads();
    for (int t = 0; t < NT; ++t) {
        const int row0 = t * 64;
        // ---- issue this tile's loads (independent of the resolve) ----
        const int w = t + 1 + wi;
        const u64 wvalid = (w < NT) ? ~0ull : 0ull;
        const int wc = (w < NT) ? w : (NT - 1);
        const u64* rp = mask + (u64)(row0 + rg * 8) * R + wc;
        u64 v0 = rp[0 * R], v1 = rp[1 * R], v2 = rp[2 * R], v3 = rp[3 * R],
            v4 = rp[4 * R], v5 = rp[5 * R], v6 = rp[6 * R], v7 = rp[7 * R];

        // ---- wave 0: prefetch next diag + serial greedy resolve ----
        u64 d_next = 0;
        if (wave == 0) {
            const int tn = (t + 1 < NT) ? (t + 1) : 0;
            d_next = diagw[tn * 64 + lane];
            const int rows = (N_BOXES - row0 >= 64) ? 64 : (N_BOXES - row0);
            const u64 valid = (rows == 64) ? ~0ull : ((1ull << rows) - 1ull);
            u64 cand = valid & ~removed[t];
            u64 kw = 0;
            while (cand) {
                int f = (int)__builtin_ctzll(cand);
                kw |= (1ull << f);
                u64 df = rdlane64(d_cur, f);
                cand &= ~(df | (1ull << f));
            }
            if (lane == 0) { kwbuf[t] = kw; kw_slot = kw; }
        }
        __syncthreads();
        // ---- masked OR + one LDS atomic per thread ----
        const u64 kw = kw_slot;
        const int rb = rg * 8;
        u64 acc = (v0 & (((kw >> (rb + 0)) & 1ull) ? ~0ull : 0ull))
                | (v1 & (((kw >> (rb + 1)) & 1ull) ? ~0ull : 0ull))
                | (v2 & (((kw >> (rb + 2)) & 1ull) ? ~0ull : 0ull))
                | (v3 & (((kw >> (rb + 3)) & 1ull) ? ~0ull : 0ull))
                | (v4 & (((kw >> (rb + 4)) & 1ull) ? ~0ull : 0ull))
                | (v5 & (((kw >> (rb + 5)) & 1ull) ? ~0ull : 0ull))
                | (v6 & (((kw >> (rb + 6)) & 1ull) ? ~0ull : 0ull))
                | (v7 & (((kw >> (rb + 7)) & 1ull) ? ~0ull : 0ull));
        acc &= wvalid;
        if (acc) atomicOr(&removed[wc], acc);
        __syncthreads();
        d_cur = d_next;
    }
    // ---- epilogue: masked scores through the sort permutation ----
    for (int p = tid; p < N_BOXES; p += 1024) {
        int orig = sidx[p];
        float s = scores[orig];
        bool k = (kwbuf[p >> 6] >> (p & 63)) & 1ull;
        out[orig] = (k && (s >= CONF_THR)) ? s : 0.0f;  // writes ALL outputs
    }
}

extern "C" void kernel_launch(void* const* d_in, const int* in_sizes, int n_in,
                              void* d_out, int out_size, void* d_ws, size_t ws_size,
                              hipStream_t stream) {
    const float* boxes  = (const float*)d_in[0];    // [6000,4]
    const float* scores = (const float*)d_in[1];    // [6000]
    float* out = (float*)d_out;                     // [6000]

    // workspace layout (k_scan's bounded tail over-reads stay inside d_ws)
    char* ws = (char*)d_ws;
    u64*    mask   = (u64*)(ws);                    // 6000*94*8 = 4,512,000 B
    u64*    diagw  = (u64*)(ws + 4512000);          // 94*64*8   =    48,128 B
    int*    sidx   = (int*)(ws + 4560128);          // 24,000 B
    float4* sboxes = (float4*)(ws + 4584128);       // 96,000 B (16B aligned)

    k_sort<<<dim3(NT), dim3(256), 0, stream>>>(scores, (const float4*)boxes, sidx, sboxes);
    k_mask<<<dim3(NT, NT), dim3(64), 0, stream>>>(sboxes, mask, diagw);
    k_scan<<<dim3(1), dim3(1024), 0, stream>>>(mask, diagw, sidx, scores, out);
}